// Round 1
// baseline (6867.876 us; speedup 1.0000x reference)
//
#include <hip/hip_runtime.h>
#include <hip/hip_bf16.h>
#include <cstdint>
#include <cstddef>

#define VOCAB  4096
#define HIDDEN 1024
#define BATCH  64
#define SEQ    256

typedef __attribute__((ext_vector_type(8))) short short8;
typedef __attribute__((ext_vector_type(4))) float f32x4;

__device__ __forceinline__ unsigned short f2bf(float f) {
    union { float f; uint32_t u; } v; v.f = f;
    uint32_t u = v.u;
    u += 0x7FFFu + ((u >> 16) & 1u);   // round-to-nearest-even
    return (unsigned short)(u >> 16);
}

// ---------------- zero init H ----------------
__global__ __launch_bounds__(256) void k_zero(float* Hf, unsigned short* Hbf) {
    int i = blockIdx.x * 256 + threadIdx.x;
    if (i < BATCH * HIDDEN) { Hf[i] = 0.f; Hbf[i] = 0; }
}

// ---------------- transpose+pack: src f32 [R][C] -> dst bf16 [C][R] ----------------
__global__ __launch_bounds__(256) void k_pack(const float* __restrict__ src,
                                              unsigned short* __restrict__ dst,
                                              int R, int C) {
    __shared__ float tile[32][33];
    int tilesC = C >> 5;
    int bx = blockIdx.x % tilesC;   // over C
    int by = blockIdx.x / tilesC;   // over R
    int tx = threadIdx.x & 31;
    int ty = threadIdx.x >> 5;      // 0..7
    int c0 = bx << 5, r0 = by << 5;
    #pragma unroll
    for (int s = 0; s < 4; ++s) {
        int r = ty + s * 8;
        tile[r][tx] = src[(size_t)(r0 + r) * C + (c0 + tx)];
    }
    __syncthreads();
    #pragma unroll
    for (int s = 0; s < 4; ++s) {
        int cc = ty + s * 8;
        dst[(size_t)(c0 + cc) * R + (r0 + tx)] = f2bf(tile[tx][cc]);
    }
}

// ---------------- step kernel 1: z & r gates ----------------
// C(64 x 2048) = Hbf(64x1024) @ [Wzh | Wrh]   (wave per 16x16 tile)
// epilogue: z = sigmoid(. + Wz_x[tok] + bz) -> zbuf
//           r = sigmoid(. + Wr_x[tok] + br) ; rHbf = bf16(r * Hf)
__global__ __launch_bounds__(256) void k_step1(
    const int* __restrict__ X,
    const float* __restrict__ Wz, const float* __restrict__ bz,
    const float* __restrict__ Wr, const float* __restrict__ br,
    const unsigned short* __restrict__ Wzh, const unsigned short* __restrict__ Wrh,
    const unsigned short* __restrict__ Hbf, const float* __restrict__ Hf,
    float* __restrict__ zbuf, unsigned short* __restrict__ rHbf, int t)
{
    int w    = threadIdx.x >> 6;
    int lane = threadIdx.x & 63;
    int nt = blockIdx.x;      // 0..127  (n tile, shared by the block's 4 waves)
    int mt = w;               // 0..3    (m tile)
    bool isz = nt < 64;
    const unsigned short* W = isz ? Wzh : Wrh;
    int ntl = nt & 63;
    int row = lane & 15;
    int kq  = (lane >> 4) << 3;   // 0,8,16,24
    const unsigned short* aptr = Hbf + (size_t)(mt * 16 + row) * HIDDEN + kq;
    const unsigned short* bptr = W   + (size_t)(ntl * 16 + row) * HIDDEN + kq;
    f32x4 acc = {0.f, 0.f, 0.f, 0.f};
    #pragma unroll 8
    for (int kk = 0; kk < HIDDEN / 32; ++kk) {
        short8 a = *(const short8*)(aptr + kk * 32);
        short8 b = *(const short8*)(bptr + kk * 32);
        acc = __builtin_amdgcn_mfma_f32_16x16x32_bf16(a, b, acc, 0, 0, 0);
    }
    int j = ntl * 16 + row;               // 0..1023 within this gate
    const float* Wemb = isz ? Wz : Wr;    // embedding part = first VOCAB rows
    float bias = isz ? bz[j] : br[j];
    #pragma unroll
    for (int r = 0; r < 4; ++r) {
        int b = mt * 16 + ((lane >> 4) << 2) + r;   // batch row
        int tok = X[b * SEQ + t];
        float pre = acc[r] + Wemb[(size_t)tok * HIDDEN + j] + bias;
        float s = 1.f / (1.f + expf(-pre));
        if (isz) zbuf[b * HIDDEN + j] = s;
        else     rHbf[b * HIDDEN + j] = f2bf(s * Hf[b * HIDDEN + j]);
    }
}

// ---------------- step kernel 2: candidate h + state update ----------------
// C(64 x 1024) = rHbf @ Whh ; h = tanh(. + Wh_x[tok] + bh)
// Hn = z*h + (1-z)*H ; write Hf, Hbf, Hhist[t]
__global__ __launch_bounds__(256) void k_step2(
    const int* __restrict__ X,
    const float* __restrict__ Wh, const float* __restrict__ bh,
    const unsigned short* __restrict__ Whh,
    const unsigned short* __restrict__ rHbf,
    const float* __restrict__ zbuf,
    float* __restrict__ Hf, unsigned short* __restrict__ Hbf,
    unsigned short* __restrict__ Hhist, int t)
{
    int w    = threadIdx.x >> 6;
    int lane = threadIdx.x & 63;
    int nt = blockIdx.x;      // 0..63
    int mt = w;               // 0..3
    int row = lane & 15;
    int kq  = (lane >> 4) << 3;
    const unsigned short* aptr = rHbf + (size_t)(mt * 16 + row) * HIDDEN + kq;
    const unsigned short* bptr = Whh  + (size_t)(nt * 16 + row) * HIDDEN + kq;
    f32x4 acc = {0.f, 0.f, 0.f, 0.f};
    #pragma unroll 8
    for (int kk = 0; kk < HIDDEN / 32; ++kk) {
        short8 a = *(const short8*)(aptr + kk * 32);
        short8 b = *(const short8*)(bptr + kk * 32);
        acc = __builtin_amdgcn_mfma_f32_16x16x32_bf16(a, b, acc, 0, 0, 0);
    }
    int j = nt * 16 + row;
    float bias = bh[j];
    #pragma unroll
    for (int r = 0; r < 4; ++r) {
        int b = mt * 16 + ((lane >> 4) << 2) + r;
        int tok = X[b * SEQ + t];
        float pre = acc[r] + Wh[(size_t)tok * HIDDEN + j] + bias;
        float h = tanhf(pre);
        float z = zbuf[b * HIDDEN + j];
        float Hold = Hf[b * HIDDEN + j];
        float Hn = z * h + (1.f - z) * Hold;
        Hf[b * HIDDEN + j] = Hn;
        unsigned short bf = f2bf(Hn);
        Hbf[b * HIDDEN + j] = bf;
        Hhist[(size_t)t * (BATCH * HIDDEN) + b * HIDDEN + j] = bf;
    }
}

// ---------------- output projection: out(16384x4096) = Hhist @ Wo + bo ----------------
// A = Hhist bf16 [16384][1024], B = WoT bf16 [4096][1024]
__global__ __launch_bounds__(256) void k_out(
    const unsigned short* __restrict__ A,
    const unsigned short* __restrict__ B,
    const float* __restrict__ bo,
    float* __restrict__ out)
{
    __shared__ __align__(16) unsigned short As[128 * 32];
    __shared__ __align__(16) unsigned short Bs[128 * 32];
    int bn = blockIdx.x & 31;
    int bm = blockIdx.x >> 5;
    int m0 = bm << 7, n0 = bn << 7;
    int tid  = threadIdx.x;
    int w    = tid >> 6, lane = tid & 63;
    int wm = w & 1, wn = w >> 1;          // 2x2 wave quadrants of 64x64
    int row = lane & 15;
    int kq  = (lane >> 4) << 3;

    f32x4 acc[4][4];
    #pragma unroll
    for (int i = 0; i < 4; ++i)
        #pragma unroll
        for (int jj = 0; jj < 4; ++jj)
            acc[i][jj] = (f32x4){0.f, 0.f, 0.f, 0.f};

    for (int k0 = 0; k0 < HIDDEN; k0 += 32) {
        // stage 128x32 A-tile and B-tile (each thread 2x16B per matrix)
        #pragma unroll
        for (int c = 0; c < 2; ++c) {
            int off  = tid * 32 + c * 16;       // byte offset in 8KB tile
            int rowi = off >> 6;                // tile row (64B rows)
            int us   = (off & 63) >> 1;         // ushort offset in row
            *(short8*)&As[rowi * 32 + us] =
                *(const short8*)&A[(size_t)(m0 + rowi) * HIDDEN + k0 + us];
            *(short8*)&Bs[rowi * 32 + us] =
                *(const short8*)&B[(size_t)(n0 + rowi) * HIDDEN + k0 + us];
        }
        __syncthreads();
        short8 a[4], b[4];
        #pragma unroll
        for (int i = 0; i < 4; ++i)
            a[i] = *(const short8*)&As[(wm * 64 + i * 16 + row) * 32 + kq];
        #pragma unroll
        for (int jj = 0; jj < 4; ++jj)
            b[jj] = *(const short8*)&Bs[(wn * 64 + jj * 16 + row) * 32 + kq];
        #pragma unroll
        for (int i = 0; i < 4; ++i)
            #pragma unroll
            for (int jj = 0; jj < 4; ++jj)
                acc[i][jj] = __builtin_amdgcn_mfma_f32_16x16x32_bf16(a[i], b[jj], acc[i][jj], 0, 0, 0);
        __syncthreads();
    }

    #pragma unroll
    for (int i = 0; i < 4; ++i) {
        #pragma unroll
        for (int jj = 0; jj < 4; ++jj) {
            int n = n0 + wn * 64 + jj * 16 + row;
            float bb = bo[n];
            #pragma unroll
            for (int r = 0; r < 4; ++r) {
                int m = m0 + wm * 64 + i * 16 + ((lane >> 4) << 2) + r;
                out[(size_t)m * VOCAB + n] = acc[i][jj][r] + bb;
            }
        }
    }
}

// ---------------- H_final copy ----------------
__global__ __launch_bounds__(256) void k_copyH(const float* __restrict__ Hf,
                                               float* __restrict__ out) {
    int i = blockIdx.x * 256 + threadIdx.x;
    if (i < BATCH * HIDDEN)
        out[(size_t)SEQ * BATCH * VOCAB + i] = Hf[i];
}

extern "C" void kernel_launch(void* const* d_in, const int* in_sizes, int n_in,
                              void* d_out, int out_size, void* d_ws, size_t ws_size,
                              hipStream_t stream) {
    const int*   X  = (const int*)  d_in[0];
    const float* Wz = (const float*)d_in[1];
    const float* bz = (const float*)d_in[2];
    const float* Wr = (const float*)d_in[3];
    const float* br = (const float*)d_in[4];
    const float* Wh = (const float*)d_in[5];
    const float* bh = (const float*)d_in[6];
    const float* Wo = (const float*)d_in[7];
    const float* bo = (const float*)d_in[8];
    float* out = (float*)d_out;
    char* ws = (char*)d_ws;

    float*          Hf    = (float*)(ws);                         // 256KB
    float*          zbuf  = (float*)(ws + (256 << 10));           // 256KB
    unsigned short* Hbf   = (unsigned short*)(ws + (512 << 10));  // 128KB
    unsigned short* rHbf  = (unsigned short*)(ws + (640 << 10));  // 128KB
    unsigned short* Wzh   = (unsigned short*)(ws + (768 << 10));  // 2MB
    unsigned short* Wrh   = Wzh + 1024 * 1024;                    // 2MB
    unsigned short* Whh   = Wrh + 1024 * 1024;                    // 2MB
    unsigned short* WoT   = Whh + 1024 * 1024;                    // 8MB
    unsigned short* Hhist = WoT + (size_t)VOCAB * HIDDEN;         // 32MB

    k_zero<<<256, 256, 0, stream>>>(Hf, Hbf);
    k_pack<<<32 * 32,  256, 0, stream>>>(Wz + (size_t)VOCAB * HIDDEN, Wzh, 1024, 1024);
    k_pack<<<32 * 32,  256, 0, stream>>>(Wr + (size_t)VOCAB * HIDDEN, Wrh, 1024, 1024);
    k_pack<<<32 * 32,  256, 0, stream>>>(Wh + (size_t)VOCAB * HIDDEN, Whh, 1024, 1024);
    k_pack<<<32 * 128, 256, 0, stream>>>(Wo, WoT, 1024, 4096);

    for (int t = 0; t < SEQ; ++t) {
        k_step1<<<128, 256, 0, stream>>>(X, Wz, bz, Wr, br, Wzh, Wrh, Hbf, Hf, zbuf, rHbf, t);
        k_step2<<<64,  256, 0, stream>>>(X, Wh, bh, Whh, rHbf, zbuf, Hf, Hbf, Hhist, t);
    }

    k_out<<<4096, 256, 0, stream>>>(Hhist, WoT, bo, out);
    k_copyH<<<256, 256, 0, stream>>>(Hf, out);
}